// Round 10
// baseline (1359.688 us; speedup 1.0000x reference)
//
#include <hip/hip_runtime.h>

// RGCN embedding, MI355X.  R10: fine CSR eliminated.  kbinA (fused-rank,
// single pass) bins edges into 128-node buckets; edge kernels process one
// bucket per block with LDS-resident accumulators (ds_add_f32) and LDS
// (node,rel) histograms for deg — kscatter2/kscan/packed/rowptr deleted.
// GEMM1 reads A as f32 directly (embb/kemb deleted).  Streaming-wave GEMMs
// with LDS-pack epilogues and XCD swizzle kept from R9.
#define N_NODES 100000
#define N_PAD   100096
#define E_EDGES 3200000
#define NB      784            // buckets of 128 nodes: 784*128 = 100352
#define BCAP    4864           // mean 4096, sd ~64 -> +12 sd
#define EPB     2048           // edges per kbinA block

typedef float f32x4 __attribute__((ext_vector_type(4)));
typedef __bf16 bf16x8 __attribute__((ext_vector_type(8)));

__device__ __forceinline__ float b2f(unsigned int u) {
    union { unsigned int i; float f; } x; x.i = u << 16; return x.f;
}
// round-to-nearest-away bf16 cast (2 ops; ties-away == RNE for random data)
__device__ __forceinline__ unsigned short f2b(float f) {
    union { float f; unsigned int i; } x; x.f = f;
    return (unsigned short)((x.i + 0x8000u) >> 16);
}

__global__ __launch_bounds__(256) void kcur(int* __restrict__ gCursor) {
    int id = blockIdx.x * 256 + threadIdx.x;
    if (id < NB) gCursor[id] = id * BCAP;
}

// w1T[j][k] = sum_b comps1[r,b]*bases1[b,k,h], j=r*32+h  (bf16, [1024][128])
__global__ __launch_bounds__(256) void kw1(const float* __restrict__ comps1,
                                           const float* __restrict__ bases1,
                                           unsigned short* __restrict__ w1T) {
    int id = blockIdx.x * 256 + threadIdx.x;
    if (id >= 1024 * 128) return;
    int k = id & 127, j = id >> 7;
    int r = j >> 5, h = j & 31;
    float s = 0.f;
#pragma unroll
    for (int b = 0; b < 16; b++)
        s += comps1[r * 16 + b] * bases1[b * 4096 + k * 32 + h];
    w1T[(size_t)j * 128 + k] = f2b(s);
}

// w2T[j2][h] = sum_b comps2[r,b]*bases2[b,h,c], j2=r*16+c  (bf16, [512][32])
__global__ __launch_bounds__(256) void kw2(const float* __restrict__ comps2,
                                           const float* __restrict__ bases2,
                                           unsigned short* __restrict__ w2T) {
    int id = blockIdx.x * 256 + threadIdx.x;
    if (id >= 512 * 32) return;
    int h = id & 31, j = id >> 5;
    int r = j >> 4, c = j & 15;
    float s = 0.f;
#pragma unroll
    for (int b = 0; b < 16; b++)
        s += comps2[r * 16 + b] * bases2[b * 512 + h * 16 + c];
    w2T[(size_t)j * 32 + h] = f2b(s);
}

// Single-pass binning: count-atomics double as rank claims (words/ranks held
// in registers); then per-bucket cursor claim; then scatter from registers.
// stage word = (frlo<<22)|(rel<<17)|to, frlo = fr & 127.
__global__ __launch_bounds__(256) void kbinA(const int* __restrict__ rel,
                                             const int* __restrict__ fr,
                                             const int* __restrict__ to,
                                             int* __restrict__ gCursor,
                                             unsigned int* __restrict__ stage) {
    __shared__ int cnt[NB];
    __shared__ int base[NB];
    int tid = threadIdx.x;
    int g0 = blockIdx.x * (EPB / 4);
    for (int i = tid; i < NB; i += 256) cnt[i] = 0;
    __syncthreads();
    unsigned int wd[8]; int bk[8], rk[8]; bool vld[2];
#pragma unroll
    for (int i = 0; i < 2; i++) {
        int g = g0 + i * 256 + tid;
        vld[i] = (g < E_EDGES / 4);
        if (vld[i]) {
            int4 f4 = ((const int4*)fr)[g];
            int4 r4 = ((const int4*)rel)[g];
            int4 t4 = ((const int4*)to)[g];
            int fa[4] = {f4.x, f4.y, f4.z, f4.w};
            int ra[4] = {r4.x, r4.y, r4.z, r4.w};
            int ta[4] = {t4.x, t4.y, t4.z, t4.w};
#pragma unroll
            for (int u = 0; u < 4; u++) {
                int ix = i * 4 + u;
                bk[ix] = fa[u] >> 7;
                wd[ix] = ((unsigned int)(fa[u] & 127) << 22) |
                         ((unsigned int)ra[u] << 17) | (unsigned int)ta[u];
                rk[ix] = atomicAdd(&cnt[bk[ix]], 1);
            }
        }
    }
    __syncthreads();
    for (int i = tid; i < NB; i += 256)
        base[i] = atomicAdd(&gCursor[i], cnt[i]);
    __syncthreads();
#pragma unroll
    for (int i = 0; i < 2; i++) {
        if (vld[i]) {
#pragma unroll
            for (int u = 0; u < 4; u++) {
                int ix = i * 4 + u;
                stage[base[bk[ix]] + rk[ix]] = wd[ix];
            }
        }
    }
}

// GEMM1 (streaming-wave, direct-f32 A, LDS-pack epilogue):
// xw[m][j] = sum_k emb[m][k]*w1T[j][k].  B-slab 64n x 128k in regs; 16 m-iters
// of 16 rows, ping-pong f32 A prefetch (rows clamped to N-1), RNA bf16 cast.
__global__ __launch_bounds__(256) void gemm1(const float* __restrict__ emb,
                                             const unsigned short* __restrict__ w1T,
                                             unsigned short* __restrict__ xw) {
    __shared__ unsigned short ldsT[4 * 16 * 136];
    int id = blockIdx.x;
    int xcd = id & 7, w = id >> 3;
    int bn = w & 15, mgl = w >> 4;
    int mg = mgl * 8 + xcd;
    if (mg >= 98) return;
    int lane = threadIdx.x & 63, wave = threadIdx.x >> 6;
    int m_ = lane & 15, q = lane >> 4;
    unsigned short* tw = &ldsT[wave * 16 * 136];
    bf16x8 B[4][4];
    const unsigned short* Bbase = w1T + (size_t)(bn * 64 + m_) * 128 + q * 8;
#pragma unroll
    for (int j = 0; j < 4; j++)
#pragma unroll
        for (int k0 = 0; k0 < 4; k0++)
            B[j][k0] = *(const bf16x8*)(Bbase + j * 16 * 128 + k0 * 32);
    int mrow0 = mg * 1024 + wave * 16;
    float4 af[2][8];
    {
        int row = min(mrow0 + m_, N_NODES - 1);
        const float* ap = emb + (size_t)row * 128 + q * 8;
#pragma unroll
        for (int k0 = 0; k0 < 4; k0++) {
            af[0][k0 * 2]     = *(const float4*)(ap + k0 * 32);
            af[0][k0 * 2 + 1] = *(const float4*)(ap + k0 * 32 + 4);
        }
    }
#pragma unroll
    for (int t = 0; t < 16; t++) {
        int m0 = mrow0 + t * 64;
        if (m0 >= N_PAD) break;
        float4* cur = af[t & 1];
        float4* nxt = af[(t + 1) & 1];
        if (t < 15 && m0 + 64 < N_PAD) {
            int row = min(mrow0 + (t + 1) * 64 + m_, N_NODES - 1);
            const float* ap = emb + (size_t)row * 128 + q * 8;
#pragma unroll
            for (int k0 = 0; k0 < 4; k0++) {
                nxt[k0 * 2]     = *(const float4*)(ap + k0 * 32);
                nxt[k0 * 2 + 1] = *(const float4*)(ap + k0 * 32 + 4);
            }
        }
        bf16x8 a[4];
#pragma unroll
        for (int k0 = 0; k0 < 4; k0++) {
            ushort4 lo, hi;
            lo.x = f2b(cur[k0 * 2].x); lo.y = f2b(cur[k0 * 2].y);
            lo.z = f2b(cur[k0 * 2].z); lo.w = f2b(cur[k0 * 2].w);
            hi.x = f2b(cur[k0 * 2 + 1].x); hi.y = f2b(cur[k0 * 2 + 1].y);
            hi.z = f2b(cur[k0 * 2 + 1].z); hi.w = f2b(cur[k0 * 2 + 1].w);
            union { ushort4 s[2]; bf16x8 v; } pk;
            pk.s[0] = lo; pk.s[1] = hi;
            a[k0] = pk.v;
        }
        f32x4 acc[4] = {};
#pragma unroll
        for (int k0 = 0; k0 < 4; k0++)
#pragma unroll
            for (int j = 0; j < 4; j++)
                acc[j] = __builtin_amdgcn_mfma_f32_16x16x32_bf16(B[j][k0], a[k0], acc[j], 0, 0, 0);
#pragma unroll
        for (int jj = 0; jj < 4; jj++) {
            ushort4 s;
            s.x = f2b(acc[jj][0]); s.y = f2b(acc[jj][1]);
            s.z = f2b(acc[jj][2]); s.w = f2b(acc[jj][3]);
            *(ushort4*)(tw + m_ * 136 + jj * 16 + q * 4) = s;
        }
        __asm__ volatile("s_waitcnt lgkmcnt(0)" ::: "memory");
#pragma unroll
        for (int ri = 0; ri < 2; ri++) {
            int row = (lane >> 3) + ri * 8;
            int c = lane & 7;
            uint4 v = *(const uint4*)(tw + row * 136 + c * 8);
            int grow = m0 + row;
            if (grow < N_NODES)
                *(uint4*)(xw + (size_t)grow * 1024 + bn * 64 + c * 8) = v;
        }
        __asm__ volatile("s_waitcnt lgkmcnt(0)" ::: "memory");
    }
}

// edge1bkt: one 128-node bucket per block.  LDS (node,rel) hist -> deg;
// gather xw rows (8 edges/wave-instr, lane=(p<<3)|sub); ds_add_f32 into the
// LDS hidden1 slice (stride 33 -> conflict-free); fused bias1+relu flush.
__global__ __launch_bounds__(256) void edge1bkt(const unsigned int* __restrict__ stage,
                                                const int* __restrict__ gCursor,
                                                const unsigned short* __restrict__ xw,
                                                const float* __restrict__ bias1,
                                                unsigned short* __restrict__ h1b) {
    __shared__ int hist2[128 * 33];
    __shared__ float hacc[128 * 33];
    int b = blockIdx.x, tid = threadIdx.x;
    int nb = gCursor[b] - b * BCAP;
    const unsigned int* sb = stage + (size_t)b * BCAP;
    for (int i = tid; i < 128 * 33; i += 256) { hist2[i] = 0; hacc[i] = 0.f; }
    __syncthreads();
    int nb4 = nb >> 2;
    for (int i4 = tid; i4 < nb4; i4 += 256) {
        uint4 p4 = ((const uint4*)sb)[i4];
        unsigned int pa[4] = {p4.x, p4.y, p4.z, p4.w};
#pragma unroll
        for (int u = 0; u < 4; u++)
            atomicAdd(&hist2[(pa[u] >> 22) * 33 + ((pa[u] >> 17) & 31)], 1);
    }
    for (int i = (nb4 << 2) + tid; i < nb; i += 256) {
        unsigned int pk = sb[i];
        atomicAdd(&hist2[(pk >> 22) * 33 + ((pk >> 17) & 31)], 1);
    }
    __syncthreads();
    int lane = tid & 63, wave = tid >> 6;
    int sub = lane & 7, p = lane >> 3;
    for (int base = wave * 8; base < nb; base += 32) {
        int e = base + p;
        if (e < nb) {
            unsigned int pk = sb[e];
            int frlo = pk >> 22, r = (pk >> 17) & 31, t_ = pk & 0x1FFFF;
            float v = 1.0f / (float)hist2[frlo * 33 + r];
            ushort4 raw = *(const ushort4*)(xw + (size_t)t_ * 1024 + (r << 5) + (sub << 2));
            float* hp = &hacc[frlo * 33 + 0];  // note: 32 cols live in stride-33 rows
            atomicAdd(hp + (sub << 2) + 0, v * b2f(raw.x));
            atomicAdd(hp + (sub << 2) + 1, v * b2f(raw.y));
            atomicAdd(hp + (sub << 2) + 2, v * b2f(raw.z));
            atomicAdd(hp + (sub << 2) + 3, v * b2f(raw.w));
        }
    }
    __syncthreads();
    for (int i = tid; i < 128 * 8; i += 256) {
        int row = i >> 3, cq = (i & 7) << 2;
        int f = b * 128 + row;
        if (f < N_NODES) {
            ushort4 o;
            o.x = f2b(fmaxf(hacc[row * 33 + cq + 0] + bias1[cq + 0], 0.f));
            o.y = f2b(fmaxf(hacc[row * 33 + cq + 1] + bias1[cq + 1], 0.f));
            o.z = f2b(fmaxf(hacc[row * 33 + cq + 2] + bias1[cq + 2], 0.f));
            o.w = f2b(fmaxf(hacc[row * 33 + cq + 3] + bias1[cq + 3], 0.f));
            *(ushort4*)(h1b + (size_t)f * 32 + cq) = o;
        }
    }
}

// GEMM2 (streaming-wave + LDS-pack epilogue): z[m][j2] = sum_h h1b[m][h]*w2T[j2][h].
__global__ __launch_bounds__(256) void gemm2(const unsigned short* __restrict__ h1b,
                                             const unsigned short* __restrict__ w2T,
                                             unsigned short* __restrict__ z) {
    __shared__ unsigned short ldsT[4 * 16 * 136];
    int id = blockIdx.x;
    int xcd = id & 7, w = id >> 3;
    int bn = w & 7, mgl = w >> 3;
    int mg = mgl * 8 + xcd;
    if (mg >= 98) return;
    int lane = threadIdx.x & 63, wave = threadIdx.x >> 6;
    int m_ = lane & 15, q = lane >> 4;
    unsigned short* tw = &ldsT[wave * 16 * 136];
    bf16x8 B[4];
    const unsigned short* Bbase = w2T + (size_t)(bn * 64 + m_) * 32 + q * 8;
#pragma unroll
    for (int j = 0; j < 4; j++)
        B[j] = *(const bf16x8*)(Bbase + j * 16 * 32);
    int mrow0 = mg * 1024 + wave * 32;
    const unsigned short* Abase = h1b + (size_t)(mrow0 + m_) * 32 + q * 8;
    bf16x8 a0[2], a1[2];
    if (mrow0 < N_PAD) {
        a0[0] = *(const bf16x8*)(Abase);
        a0[1] = *(const bf16x8*)(Abase + 16 * 32);
    }
#pragma unroll
    for (int t = 0; t < 8; t++) {
        int m0 = mrow0 + t * 128;
        if (m0 >= N_PAD) break;
        bf16x8* acur = (t & 1) ? a1 : a0;
        bf16x8* anext = (t & 1) ? a0 : a1;
        if (t < 7 && m0 + 128 < N_PAD) {
            anext[0] = *(const bf16x8*)(Abase + (size_t)(t + 1) * 128 * 32);
            anext[1] = *(const bf16x8*)(Abase + (size_t)(t + 1) * 128 * 32 + 16 * 32);
        }
        f32x4 acc[2][4] = {};
#pragma unroll
        for (int i = 0; i < 2; i++)
#pragma unroll
            for (int j = 0; j < 4; j++)
                acc[i][j] = __builtin_amdgcn_mfma_f32_16x16x32_bf16(B[j], acur[i], acc[i][j], 0, 0, 0);
#pragma unroll
        for (int i = 0; i < 2; i++) {
#pragma unroll
            for (int jj = 0; jj < 4; jj++) {
                ushort4 s;
                s.x = f2b(acc[i][jj][0]); s.y = f2b(acc[i][jj][1]);
                s.z = f2b(acc[i][jj][2]); s.w = f2b(acc[i][jj][3]);
                *(ushort4*)(tw + m_ * 136 + jj * 16 + q * 4) = s;
            }
            __asm__ volatile("s_waitcnt lgkmcnt(0)" ::: "memory");
#pragma unroll
            for (int ri = 0; ri < 2; ri++) {
                int row = (lane >> 3) + ri * 8;
                int c = lane & 7;
                uint4 v = *(const uint4*)(tw + row * 136 + c * 8);
                int grow = m0 + i * 16 + row;
                if (grow < N_NODES)
                    *(uint4*)(z + (size_t)grow * 512 + bn * 64 + c * 8) = v;
            }
            __asm__ volatile("s_waitcnt lgkmcnt(0)" ::: "memory");
        }
    }
}

// edge2bkt: one 128-node bucket per block.  LDS hist -> deg; gather z rows
// (16 edges/wave-instr, lane=(p<<2)|sub); ds_add_f32 into LDS out slice
// (stride 17); fused bias2 float4 flush.
__global__ __launch_bounds__(256) void edge2bkt(const unsigned int* __restrict__ stage,
                                                const int* __restrict__ gCursor,
                                                const unsigned short* __restrict__ z,
                                                const float* __restrict__ bias2,
                                                float* __restrict__ out) {
    __shared__ int hist2[128 * 33];
    __shared__ float oacc[128 * 17];
    int b = blockIdx.x, tid = threadIdx.x;
    int nb = gCursor[b] - b * BCAP;
    const unsigned int* sb = stage + (size_t)b * BCAP;
    for (int i = tid; i < 128 * 33; i += 256) hist2[i] = 0;
    for (int i = tid; i < 128 * 17; i += 256) oacc[i] = 0.f;
    __syncthreads();
    int nb4 = nb >> 2;
    for (int i4 = tid; i4 < nb4; i4 += 256) {
        uint4 p4 = ((const uint4*)sb)[i4];
        unsigned int pa[4] = {p4.x, p4.y, p4.z, p4.w};
#pragma unroll
        for (int u = 0; u < 4; u++)
            atomicAdd(&hist2[(pa[u] >> 22) * 33 + ((pa[u] >> 17) & 31)], 1);
    }
    for (int i = (nb4 << 2) + tid; i < nb; i += 256) {
        unsigned int pk = sb[i];
        atomicAdd(&hist2[(pk >> 22) * 33 + ((pk >> 17) & 31)], 1);
    }
    __syncthreads();
    int lane = tid & 63, wave = tid >> 6;
    int sub = lane & 3, p = lane >> 2;
    for (int base = wave * 16; base < nb; base += 64) {
        int e = base + p;
        if (e < nb) {
            unsigned int pk = sb[e];
            int frlo = pk >> 22, r = (pk >> 17) & 31, t_ = pk & 0x1FFFF;
            float v = 1.0f / (float)hist2[frlo * 33 + r];
            ushort4 raw = *(const ushort4*)(z + (size_t)t_ * 512 + (r << 4) + (sub << 2));
            float* op = &oacc[frlo * 17 + 0];
            atomicAdd(op + (sub << 2) + 0, v * b2f(raw.x));
            atomicAdd(op + (sub << 2) + 1, v * b2f(raw.y));
            atomicAdd(op + (sub << 2) + 2, v * b2f(raw.z));
            atomicAdd(op + (sub << 2) + 3, v * b2f(raw.w));
        }
    }
    __syncthreads();
    for (int i = tid; i < 128 * 4; i += 256) {
        int row = i >> 2, cq = (i & 3) << 2;
        int f = b * 128 + row;
        if (f < N_NODES) {
            float4 o;
            o.x = oacc[row * 17 + cq + 0] + bias2[cq + 0];
            o.y = oacc[row * 17 + cq + 1] + bias2[cq + 1];
            o.z = oacc[row * 17 + cq + 2] + bias2[cq + 2];
            o.w = oacc[row * 17 + cq + 3] + bias2[cq + 3];
            *(float4*)(out + (size_t)f * 16 + cq) = o;
        }
    }
}

extern "C" void kernel_launch(void* const* d_in, const int* in_sizes, int n_in,
                              void* d_out, int out_size, void* d_ws, size_t ws_size,
                              hipStream_t stream) {
    (void)in_sizes; (void)n_in; (void)out_size; (void)ws_size;
    const float* emb    = (const float*)d_in[0];
    const float* comps1 = (const float*)d_in[1];
    const float* bases1 = (const float*)d_in[2];
    const float* comps2 = (const float*)d_in[3];
    const float* bases2 = (const float*)d_in[4];
    const float* bias1  = (const float*)d_in[5];
    const float* bias2  = (const float*)d_in[6];
    const int* rel = (const int*)d_in[7];
    const int* fr  = (const int*)d_in[8];
    const int* to  = (const int*)d_in[9];
    float* out = (float*)d_out;
    char* ws = (char*)d_ws;

    // workspace layout (bytes); total ~226.8 MB
    int* gCursor         = (int*)(ws);                        // [0, 4,096)
    unsigned short* h1b  = (unsigned short*)(ws + 4096);      // 6,406,144 (N_PAD x 32)
    unsigned short* w1T  = (unsigned short*)(ws + 6410240);   // 262,144
    unsigned short* w2T  = (unsigned short*)(ws + 6672384);   // 32,768
    unsigned int* stage  = (unsigned int*)(ws + 6705152);     // 15,254,528 (NB x BCAP x 4)
    unsigned short* xw   = (unsigned short*)(ws + 21959680);  // 204,800,000
    unsigned short* z    = xw;   // alias: xw dead (edge1bkt done) before gemm2 writes z

    kcur<<<4, 256, 0, stream>>>(gCursor);
    kw1<<<512, 256, 0, stream>>>(comps1, bases1, w1T);
    kw2<<<64, 256, 0, stream>>>(comps2, bases2, w2T);
    kbinA<<<(E_EDGES + EPB - 1) / EPB, 256, 0, stream>>>(rel, fr, to, gCursor, stage);
    gemm1<<<1664, 256, 0, stream>>>(emb, w1T, xw);     // 8 xcd * 16 bn * 13 mgl
    edge1bkt<<<NB, 256, 0, stream>>>(stage, gCursor, xw, bias1, h1b);
    gemm2<<<832, 256, 0, stream>>>(h1b, w2T, z);       // 8 xcd * 8 bn * 13 mgl
    edge2bkt<<<NB, 256, 0, stream>>>(stage, gCursor, z, bias2, out);
}